// Round 1
// 1982.926 us; speedup vs baseline: 1.0874x; 1.0874x over previous
//
#include <hip/hip_runtime.h>
#include <hip/hip_bf16.h>
#include <cstdint>
#include <cstddef>

// Problem constants (TimeEmbedder): B=32768 rows, DIM=1024, HID=4096
#define NB   32768
#define DIM_ 1024
#define HID_ 4096

typedef __attribute__((ext_vector_type(4))) float floatx4;
typedef __attribute__((ext_vector_type(8))) short bf16x8;

__device__ __forceinline__ short f2bf(float v) {
  __hip_bfloat16 b = __float2bfloat16(v);   // RNE
  union { __hip_bfloat16 b; short s; } u; u.b = b; return u.s;
}

__device__ __forceinline__ void async_copy16(const short* g, short* l) {
  __builtin_amdgcn_global_load_lds(
      (const __attribute__((address_space(1))) void*)g,
      (__attribute__((address_space(3))) void*)l, 16, 0, 0);
}

// ---------------------------------------------------------------------------
// Kernel 1: positional embedding + layernorm (unbiased std), bf16 output.
// One wave per row; lane handles 8 freqs (8 cos + 8 sin outputs).
// ---------------------------------------------------------------------------
__global__ void embed_ln_kernel(const float* __restrict__ t, short* __restrict__ out) {
  const int lane = threadIdx.x & 63;
  const int row  = blockIdx.x * 4 + (threadIdx.x >> 6);
  const float x = t[row] * 1000.0f;             // TIME_SCALING
  const float kf = -0.026003341251564478f;      // log2(1e-4)/511
  float cv[8], sv[8];
  float sum = 0.f, sumsq = 0.f;
#pragma unroll
  for (int i = 0; i < 8; ++i) {
    const int f = lane * 8 + i;                 // 0..511
    const float freq = exp2f(kf * (float)f);
    const float ang  = x * freq;
    float s, c;
    sincosf(ang, &s, &c);
    cv[i] = c; sv[i] = s;
    sum   += c + s;
    sumsq += c * c + s * s;
  }
#pragma unroll
  for (int m = 1; m < 64; m <<= 1) {
    sum   += __shfl_xor(sum,   m, 64);
    sumsq += __shfl_xor(sumsq, m, 64);
  }
  const float mean = sum * (1.0f / 1024.0f);
  const float var  = (sumsq - sum * sum * (1.0f / 1024.0f)) * (1.0f / 1023.0f);
  const float rstd = rsqrtf(var);
  bf16x8 pc, ps;
#pragma unroll
  for (int i = 0; i < 8; ++i) {
    pc[i] = f2bf((cv[i] - mean) * rstd);
    ps[i] = f2bf((sv[i] - mean) * rstd);
  }
  *(bf16x8*)&out[(size_t)row * 1024 + lane * 8]       = pc;  // cos half
  *(bf16x8*)&out[(size_t)row * 1024 + 512 + lane * 8] = ps;  // sin half
}

// ---------------------------------------------------------------------------
// Kernel 2: transpose fp32 [R,C] -> bf16 [C,R] (tiled, coalesced both ways)
// ---------------------------------------------------------------------------
__global__ void transpose_f32_bf16(const float* __restrict__ in, short* __restrict__ out,
                                   int R, int C) {
  __shared__ float tile[32][33];                // +1 pad: no bank conflicts
  const int tx = threadIdx.x, ty = threadIdx.y;
  const int col0 = blockIdx.x * 32, row0 = blockIdx.y * 32;
#pragma unroll
  for (int j = 0; j < 4; ++j)
    tile[ty + 8 * j][tx] = in[(size_t)(row0 + ty + 8 * j) * C + col0 + tx];
  __syncthreads();
#pragma unroll
  for (int j = 0; j < 4; ++j)
    out[(size_t)(col0 + ty + 8 * j) * R + row0 + tx] = f2bf(tile[tx][ty + 8 * j]);
}

// ---------------------------------------------------------------------------
// Kernel 3/4: C = A[M,K] @ Bt[N,K]^T + bias, optional fused SiLU + bf16 out.
//
// 256x256 tile, 512 threads (8 waves, 2Mx4N), per-wave 128x64 output.
// k-slice-ring pipeline: one BK=128 LDS buffer split into 4 slice-major
// regions [4][256][32]. Phase p (4 phases/K-tile):
//   s_waitcnt vmcnt(12)          <- slice p landed (issued 4 phases ago)
//   s_barrier                    <- ... for ALL waves
//   ds_read 12x b128 frags       <- conflict-free: 64B rows, multiplicity 8
//   s_waitcnt lgkmcnt(0); s_barrier  <- region p free for overwrite
//   issue 4x global_load_lds     <- slice p of NEXT K-tile into region p
//   setprio(1); 32x MFMA; setprio(0)
// vmcnt never drains to 0 in the main loop (T3+T4). Last tile prefetches
// kt=0 garbage (never read) to keep the count uniform.
// ---------------------------------------------------------------------------
template <bool SILU>
__launch_bounds__(512, 2)
__global__ void gemm_bt(const short* __restrict__ A,   // [M,K] bf16
                        const short* __restrict__ Bt,  // [N,K] bf16
                        const float* __restrict__ bias,// [N] fp32
                        void* __restrict__ Cv,         // SILU: bf16 [M,N] else fp32
                        int K) {
  constexpr int N   = HID_;
  constexpr int NBX = N / 256;             // 16
  constexpr int NWG = (NB / 256) * NBX;    // 2048 (NWG % 8 == 0 -> bijective)
  __shared__ __align__(16) short As[4][256][32];   // 64 KB
  __shared__ __align__(16) short Bs[4][256][32];   // 64 KB

  const int tid  = threadIdx.x;
  const int lane = tid & 63;
  const int wave = tid >> 6;
  const int wr = (wave >> 2) * 128;        // wave row offset in tile
  const int wc = (wave & 3) * 64;          // wave col offset in tile

  // T1: XCD-contiguous chunk swizzle + group-M(8) L2 tiling
  const int sid = (blockIdx.x & 7) * (NWG >> 3) + (blockIdx.x >> 3);
  constexpr int GSZ = 8 * NBX;             // 128 blocks per group-stripe
  const int g  = sid / GSZ;
  const int rr = sid % GSZ;
  const int row0 = (g * 8 + (rr & 7)) * 256;
  const int col0 = (rr >> 3) * 256;

  const short* Ag = A  + (size_t)row0 * K;
  const short* Bg = Bt + (size_t)col0 * K;

  // staging: one slice = 256x32 bf16 = 16KB per matrix = 2x16B/thread each
  const int c0  = tid,      c1  = tid + 512;
  const int r0c = c0 >> 2,  k0c = (c0 & 3) << 3;
  const int r1c = c1 >> 2,  k1c = (c1 & 3) << 3;

#define STAGE(P_, KT_)                                                         \
  do {                                                                         \
    async_copy16(Ag + (size_t)r0c * K + (KT_) + k0c, &As[P_][0][0] + c0 * 8);  \
    async_copy16(Ag + (size_t)r1c * K + (KT_) + k1c, &As[P_][0][0] + c1 * 8);  \
    async_copy16(Bg + (size_t)r0c * K + (KT_) + k0c, &Bs[P_][0][0] + c0 * 8);  \
    async_copy16(Bg + (size_t)r1c * K + (KT_) + k1c, &Bs[P_][0][0] + c1 * 8);  \
  } while (0)

  // prologue: fill all 4 slices of K-tile 0 (16 loads in flight)
  STAGE(0, 0); STAGE(1, 32); STAGE(2, 64); STAGE(3, 96);

  floatx4 acc[8][4] = {};
  const int ra = lane & 15;                // fragment row within 16
  const int ka = (lane >> 4) << 3;         // fragment k offset (0,8,16,24)

  const int nT = K >> 7;                   // K / 128
  for (int t = 0; t < nT; ++t) {
    const int ktn = (t + 1 < nT) ? ((t + 1) << 7) : 0;  // wrap on last (garbage, unread)
#pragma unroll
    for (int p = 0; p < 4; ++p) {
      // slice p of tile t landed (own loads oldest-4 of <=16) + all waves there
      asm volatile("s_waitcnt vmcnt(12)\n\ts_barrier" ::: "memory");
      bf16x8 a[8], b[4];
#pragma unroll
      for (int m = 0; m < 8; ++m)
        a[m] = *(const bf16x8*)&As[p][wr + m * 16 + ra][ka];
#pragma unroll
      for (int n = 0; n < 4; ++n)
        b[n] = *(const bf16x8*)&Bs[p][wc + n * 16 + ra][ka];
      // all waves' reads of region p complete -> safe to overwrite
      asm volatile("s_waitcnt lgkmcnt(0)\n\ts_barrier" ::: "memory");
      STAGE(p, ktn + p * 32);              // slice p of tile t+1, 4-phase-deep
      __builtin_amdgcn_sched_barrier(0);   // keep MFMAs below the stage issues
      __builtin_amdgcn_s_setprio(1);
#pragma unroll
      for (int m = 0; m < 8; ++m)
#pragma unroll
        for (int n = 0; n < 4; ++n)
          acc[m][n] = __builtin_amdgcn_mfma_f32_16x16x32_bf16(a[m], b[n], acc[m][n], 0, 0, 0);
      __builtin_amdgcn_s_setprio(0);
    }
  }
  asm volatile("s_waitcnt vmcnt(0)" ::: "memory");  // drain tail garbage loads
#undef STAGE

  // Epilogue. C/D layout (m89-verified): col = lane&15, row = (lane>>4)*4 + reg
  const int cc = lane & 15;
  const int cr = (lane >> 4) * 4;
  float bv[4];
#pragma unroll
  for (int n = 0; n < 4; ++n) bv[n] = bias[col0 + wc + n * 16 + cc];
#pragma unroll
  for (int m = 0; m < 8; ++m) {
#pragma unroll
    for (int n = 0; n < 4; ++n) {
      const int gc = col0 + wc + n * 16 + cc;
#pragma unroll
      for (int r = 0; r < 4; ++r) {
        const int gr = row0 + wr + m * 16 + cr + r;
        float v = acc[m][n][r] + bv[n];
        if constexpr (SILU) {
          v = v * (1.0f / (1.0f + __expf(-v)));
          ((short*)Cv)[(size_t)gr * N + gc] = f2bf(v);
        } else {
          ((float*)Cv)[(size_t)gr * N + gc] = v;
        }
      }
    }
  }
}

// ---------------------------------------------------------------------------
extern "C" void kernel_launch(void* const* d_in, const int* in_sizes, int n_in,
                              void* d_out, int out_size, void* d_ws, size_t ws_size,
                              hipStream_t stream) {
  const float* t  = (const float*)d_in[0];   // [32768]
  const float* W1 = (const float*)d_in[1];   // [1024,4096]
  const float* b1 = (const float*)d_in[2];   // [4096]
  const float* W2 = (const float*)d_in[3];   // [4096,4096]
  const float* b2 = (const float*)d_in[4];   // [4096]
  float* out = (float*)d_out;                // [32768,4096] fp32

  // workspace layout (all 16B aligned)
  char* ws = (char*)d_ws;
  short* timeN = (short*)(ws);                                          // 64 MB  [32768,1024] bf16
  short* W1t   = (short*)(ws + (size_t)67108864);                       // 8 MB   [4096,1024]  bf16
  short* W2t   = (short*)(ws + (size_t)67108864 + 8388608);             // 32 MB  [4096,4096]  bf16
  short* h     = (short*)(ws + (size_t)67108864 + 8388608 + 33554432);  // 256 MB [32768,4096] bf16

  embed_ln_kernel<<<NB / 4, 256, 0, stream>>>(t, timeN);
  transpose_f32_bf16<<<dim3(4096 / 32, 1024 / 32), dim3(32, 8), 0, stream>>>(W1, W1t, 1024, 4096);
  transpose_f32_bf16<<<dim3(4096 / 32, 4096 / 32), dim3(32, 8), 0, stream>>>(W2, W2t, 4096, 4096);
  gemm_bt<true ><<<dim3(2048), dim3(512), 0, stream>>>(timeN, W1t, b1, (void*)h,   DIM_);
  gemm_bt<false><<<dim3(2048), dim3(512), 0, stream>>>(h,     W2t, b2, (void*)out, HID_);
}

// Round 2
// 1843.677 us; speedup vs baseline: 1.1695x; 1.0755x over previous
//
#include <hip/hip_runtime.h>
#include <hip/hip_bf16.h>
#include <cstdint>
#include <cstddef>

// Problem constants (TimeEmbedder): B=32768 rows, DIM=1024, HID=4096
#define NB   32768
#define DIM_ 1024
#define HID_ 4096

typedef __attribute__((ext_vector_type(4))) float floatx4;
typedef __attribute__((ext_vector_type(8))) short bf16x8;

__device__ __forceinline__ short f2bf(float v) {
  __hip_bfloat16 b = __float2bfloat16(v);   // RNE
  union { __hip_bfloat16 b; short s; } u; u.b = b; return u.s;
}

__device__ __forceinline__ void async_copy16(const short* g, short* l) {
  __builtin_amdgcn_global_load_lds(
      (const __attribute__((address_space(1))) void*)g,
      (__attribute__((address_space(3))) void*)l, 16, 0, 0);
}

// ---------------------------------------------------------------------------
// Kernel 1: positional embedding + layernorm (unbiased std), bf16 output.
// One wave per row; lane handles 8 freqs (8 cos + 8 sin outputs).
// ---------------------------------------------------------------------------
__global__ void embed_ln_kernel(const float* __restrict__ t, short* __restrict__ out) {
  const int lane = threadIdx.x & 63;
  const int row  = blockIdx.x * 4 + (threadIdx.x >> 6);
  const float x = t[row] * 1000.0f;             // TIME_SCALING
  const float kf = -0.026003341251564478f;      // log2(1e-4)/511
  float cv[8], sv[8];
  float sum = 0.f, sumsq = 0.f;
#pragma unroll
  for (int i = 0; i < 8; ++i) {
    const int f = lane * 8 + i;                 // 0..511
    const float freq = exp2f(kf * (float)f);
    const float ang  = x * freq;
    float s, c;
    sincosf(ang, &s, &c);
    cv[i] = c; sv[i] = s;
    sum   += c + s;
    sumsq += c * c + s * s;
  }
#pragma unroll
  for (int m = 1; m < 64; m <<= 1) {
    sum   += __shfl_xor(sum,   m, 64);
    sumsq += __shfl_xor(sumsq, m, 64);
  }
  const float mean = sum * (1.0f / 1024.0f);
  const float var  = (sumsq - sum * sum * (1.0f / 1024.0f)) * (1.0f / 1023.0f);
  const float rstd = rsqrtf(var);
  bf16x8 pc, ps;
#pragma unroll
  for (int i = 0; i < 8; ++i) {
    pc[i] = f2bf((cv[i] - mean) * rstd);
    ps[i] = f2bf((sv[i] - mean) * rstd);
  }
  *(bf16x8*)&out[(size_t)row * 1024 + lane * 8]       = pc;  // cos half
  *(bf16x8*)&out[(size_t)row * 1024 + 512 + lane * 8] = ps;  // sin half
}

// ---------------------------------------------------------------------------
// Kernel 2: transpose fp32 [R,C] -> bf16 [C,R] (tiled, coalesced both ways)
// ---------------------------------------------------------------------------
__global__ void transpose_f32_bf16(const float* __restrict__ in, short* __restrict__ out,
                                   int R, int C) {
  __shared__ float tile[32][33];                // +1 pad: no bank conflicts
  const int tx = threadIdx.x, ty = threadIdx.y;
  const int col0 = blockIdx.x * 32, row0 = blockIdx.y * 32;
#pragma unroll
  for (int j = 0; j < 4; ++j)
    tile[ty + 8 * j][tx] = in[(size_t)(row0 + ty + 8 * j) * C + col0 + tx];
  __syncthreads();
#pragma unroll
  for (int j = 0; j < 4; ++j)
    out[(size_t)(col0 + ty + 8 * j) * R + row0 + tx] = f2bf(tile[tx][ty + 8 * j]);
}

// ---------------------------------------------------------------------------
// Kernel 3/4: C = A[M,K] @ Bt[N,K]^T + bias, optional fused SiLU + bf16 out.
//
// 256x256 tile, 512 threads (8 waves, 2Mx4N), per-wave 128x64 output.
// k-slice-ring pipeline: one BK=128 LDS buffer split into 4 slice-major
// regions [4][256][32]. Phase p (4 phases/K-tile):
//   s_waitcnt vmcnt(12); s_barrier    <- slice p landed (issued 4 phases ago)
//   ds_read 12x b128 frags            <- T2 slot-swizzled, 2 words/bank
//   s_waitcnt lgkmcnt(0); s_barrier   <- region p free for overwrite
//   issue 4x global_load_lds          <- slice p of NEXT K-tile into region p
//   setprio(1); 32x MFMA; setprio(0)
// vmcnt never drains to 0 in the main loop (T3+T4).
//
// T2 slot swizzle (rule 21: both-sides-or-neither): physical 16B chunk for
// (row, kslot) = row*4 + (kslot ^ ((row>>1)&3)). LDS dest of global_load_lds
// stays LINEAR; the global SOURCE k-offset is permuted; reads apply the same
// involution. Spread check (16-lane frag group, rows r..r+15, fixed kslot):
// chunk mod 8 = {0,4,1,5,2,6,3,7} x2 -> all 8 four-bank groups, 2 words/bank.
// Read side: ((row>>1)&3) == ((ra>>1)&3) since wr+m*16 is 16-aligned ->
// per-lane constant, zero extra VALU in the loop.
// ---------------------------------------------------------------------------
template <bool SILU>
__launch_bounds__(512, 2)
__global__ void gemm_bt(const short* __restrict__ A,   // [M,K] bf16
                        const short* __restrict__ Bt,  // [N,K] bf16
                        const float* __restrict__ bias,// [N] fp32
                        void* __restrict__ Cv,         // SILU: bf16 [M,N] else fp32
                        int K) {
  constexpr int N   = HID_;
  constexpr int NBX = N / 256;             // 16
  constexpr int NWG = (NB / 256) * NBX;    // 2048 (NWG % 8 == 0 -> bijective)
  __shared__ __align__(16) short As[4][256][32];   // 64 KB
  __shared__ __align__(16) short Bs[4][256][32];   // 64 KB

  const int tid  = threadIdx.x;
  const int lane = tid & 63;
  const int wave = tid >> 6;
  const int wr = (wave >> 2) * 128;        // wave row offset in tile
  const int wc = (wave & 3) * 64;          // wave col offset in tile

  // T1: XCD-contiguous chunk swizzle + group-M(8) L2 tiling
  const int sid = (blockIdx.x & 7) * (NWG >> 3) + (blockIdx.x >> 3);
  constexpr int GSZ = 8 * NBX;             // 128 blocks per group-stripe
  const int g  = sid / GSZ;
  const int rr = sid % GSZ;
  const int row0 = (g * 8 + (rr & 7)) * 256;
  const int col0 = (rr >> 3) * 256;

  const short* Ag = A  + (size_t)row0 * K;
  const short* Bg = Bt + (size_t)col0 * K;

  // staging: one slice = 256x32 bf16 = 16KB per matrix = 2x16B/thread each.
  // chunk c -> row = c>>2, SOURCE kslot = (c&3) ^ ((c>>3)&3)  (T2 swizzle)
  const int c0  = tid,      c1  = tid + 512;
  const int r0c = c0 >> 2,  k0c = (((c0 & 3) ^ ((c0 >> 3) & 3)) << 3);
  const int r1c = c1 >> 2,  k1c = (((c1 & 3) ^ ((c1 >> 3) & 3)) << 3);

#define STAGE(P_, KT_)                                                         \
  do {                                                                         \
    async_copy16(Ag + (size_t)r0c * K + (KT_) + k0c, &As[P_][0][0] + c0 * 8);  \
    async_copy16(Ag + (size_t)r1c * K + (KT_) + k1c, &As[P_][0][0] + c1 * 8);  \
    async_copy16(Bg + (size_t)r0c * K + (KT_) + k0c, &Bs[P_][0][0] + c0 * 8);  \
    async_copy16(Bg + (size_t)r1c * K + (KT_) + k1c, &Bs[P_][0][0] + c1 * 8);  \
  } while (0)

  // prologue: fill all 4 slices of K-tile 0 (16 loads in flight)
  STAGE(0, 0); STAGE(1, 32); STAGE(2, 64); STAGE(3, 96);

  floatx4 acc[8][4] = {};
  const int ra = lane & 15;                          // fragment row within 16
  const int kaSw = (((lane >> 4) ^ ((ra >> 1) & 3)) << 3);  // swizzled k-slot (elements)

  const int nT = K >> 7;                   // K / 128
  for (int t = 0; t < nT; ++t) {
    const int ktn = (t + 1 < nT) ? ((t + 1) << 7) : 0;  // wrap on last (garbage, unread)
#pragma unroll
    for (int p = 0; p < 4; ++p) {
      // slice p of tile t landed (own loads oldest-4 of <=16) + all waves there
      asm volatile("s_waitcnt vmcnt(12)\n\ts_barrier" ::: "memory");
      bf16x8 a[8], b[4];
#pragma unroll
      for (int m = 0; m < 8; ++m)
        a[m] = *(const bf16x8*)&As[p][wr + m * 16 + ra][kaSw];
#pragma unroll
      for (int n = 0; n < 4; ++n)
        b[n] = *(const bf16x8*)&Bs[p][wc + n * 16 + ra][kaSw];
      // all waves' reads of region p complete -> safe to overwrite
      asm volatile("s_waitcnt lgkmcnt(0)\n\ts_barrier" ::: "memory");
      STAGE(p, ktn + p * 32);              // slice p of tile t+1, 4-phase-deep
      __builtin_amdgcn_sched_barrier(0);   // keep MFMAs below the stage issues
      __builtin_amdgcn_s_setprio(1);
#pragma unroll
      for (int m = 0; m < 8; ++m)
#pragma unroll
        for (int n = 0; n < 4; ++n)
          acc[m][n] = __builtin_amdgcn_mfma_f32_16x16x32_bf16(a[m], b[n], acc[m][n], 0, 0, 0);
      __builtin_amdgcn_s_setprio(0);
    }
  }
  asm volatile("s_waitcnt vmcnt(0)" ::: "memory");  // drain tail garbage loads
#undef STAGE

  // Epilogue. C/D layout (m89-verified): col = lane&15, row = (lane>>4)*4 + reg
  const int cc = lane & 15;
  const int cr = (lane >> 4) * 4;
  float bv[4];
#pragma unroll
  for (int n = 0; n < 4; ++n) bv[n] = bias[col0 + wc + n * 16 + cc];
#pragma unroll
  for (int m = 0; m < 8; ++m) {
#pragma unroll
    for (int n = 0; n < 4; ++n) {
      const int gc = col0 + wc + n * 16 + cc;
#pragma unroll
      for (int r = 0; r < 4; ++r) {
        const int gr = row0 + wr + m * 16 + cr + r;
        float v = acc[m][n][r] + bv[n];
        if constexpr (SILU) {
          v = v * (1.0f / (1.0f + __expf(-v)));
          ((short*)Cv)[(size_t)gr * N + gc] = f2bf(v);
        } else {
          ((float*)Cv)[(size_t)gr * N + gc] = v;
        }
      }
    }
  }
}

// ---------------------------------------------------------------------------
extern "C" void kernel_launch(void* const* d_in, const int* in_sizes, int n_in,
                              void* d_out, int out_size, void* d_ws, size_t ws_size,
                              hipStream_t stream) {
  const float* t  = (const float*)d_in[0];   // [32768]
  const float* W1 = (const float*)d_in[1];   // [1024,4096]
  const float* b1 = (const float*)d_in[2];   // [4096]
  const float* W2 = (const float*)d_in[3];   // [4096,4096]
  const float* b2 = (const float*)d_in[4];   // [4096]
  float* out = (float*)d_out;                // [32768,4096] fp32

  // workspace layout (all 16B aligned)
  char* ws = (char*)d_ws;
  short* timeN = (short*)(ws);                                          // 64 MB  [32768,1024] bf16
  short* W1t   = (short*)(ws + (size_t)67108864);                       // 8 MB   [4096,1024]  bf16
  short* W2t   = (short*)(ws + (size_t)67108864 + 8388608);             // 32 MB  [4096,4096]  bf16
  short* h     = (short*)(ws + (size_t)67108864 + 8388608 + 33554432);  // 256 MB [32768,4096] bf16

  embed_ln_kernel<<<NB / 4, 256, 0, stream>>>(t, timeN);
  transpose_f32_bf16<<<dim3(4096 / 32, 1024 / 32), dim3(32, 8), 0, stream>>>(W1, W1t, 1024, 4096);
  transpose_f32_bf16<<<dim3(4096 / 32, 4096 / 32), dim3(32, 8), 0, stream>>>(W2, W2t, 4096, 4096);
  gemm_bt<true ><<<dim3(2048), dim3(512), 0, stream>>>(timeN, W1t, b1, (void*)h,   DIM_);
  gemm_bt<false><<<dim3(2048), dim3(512), 0, stream>>>(h,     W2t, b2, (void*)out, HID_);
}